// Round 14
// baseline (132.486 us; speedup 1.0000x reference)
//
#include <hip/hip_runtime.h>
#include <math.h>

// SO3 convolution lmax=2 — memset + prep(bucket->pos) + edge-parallel compute
// (R8's proven 62%-occupancy shape, atomics replaced by dense slot stores) +
// streaming reduce.
//   K0) hipMemsetAsync(cnt) — tiny.
//   K1) prep_kernel: p = atomicAdd(cnt[idx_i[e]]); pos[e] = a*CAP+p
//       (dense per-atom slot id; overflow -> trash row A*CAP).
//   K2) so3_edge_slots: ONE wave per edge (12000 waves, high occupancy).
//       Y -> wave-private LDS, M via LDS atomics (~3/lane), radial filter
//       Wf pass, x[idx_j] gather, 9x9 contract — identical math to R8 —
//       then 9 PLAIN coalesced float2 stores to slots[pos[e]].
//       Tests the theory that R8's 100us was atomic-RMW-writeback-bound.
//   K3) reduce_kernel: 2 waves per atom (s-dim split 0..4 / 5..8, no
//       cross-wave combine); sums the atom's CONTIGUOUS slot rows -> out.
//       deg-0 atoms store zeros. No global atomics anywhere after prep.
//   Fallback (ws too small): R8 fused-atomic edge kernel.

#define S9     9
#define MROW   12
#define MSZ    (S9 * MROW)      // 108
#define NF     128
#define NRAD   20
#define CAP    32               // slots per atom (P(deg>32) ~ 0 for Poisson(10))
#define ROWF   (S9 * NF)        // 1152 floats per slot row

__device__ inline float2 f2fma(float a, float2 b, float2 c) {
    return make_float2(fmaf(a, b.x, c.x), fmaf(a, b.y, c.y));
}

// ---------- K1: bucket -> dense slot position ----------
__global__ __launch_bounds__(256) void prep_kernel(
    const int* __restrict__ idx_i, int E, int A,
    int* __restrict__ cnt,          // [A], pre-zeroed
    int* __restrict__ pos)          // [E] slot row id (or trash row A*CAP)
{
    int e = blockIdx.x * 256 + threadIdx.x;
    if (e < E) {
        int a = idx_i[e];
        int p = atomicAdd(&cnt[a], 1);
        pos[e] = (p < CAP) ? (a * CAP + p) : (A * CAP);
    }
}

// ---------- K2: one wave per edge, plain slot stores ----------
__global__ __launch_bounds__(256) void so3_edge_slots(
    const float* __restrict__ x,        // [A, 9, 128]
    const float* __restrict__ radial,   // [E, 20]
    const float* __restrict__ dir,      // [E, 3]
    const float* __restrict__ cutoff,   // [E]
    const float* __restrict__ Wf,       // [20, 384]
    const float* __restrict__ bf,       // [384]
    const float* __restrict__ cg_vals,
    const int* __restrict__ idx_j,
    const int* __restrict__ cg_i1,
    const int* __restrict__ cg_i2,
    const int* __restrict__ cg_i3,
    int ncg, int E,
    const int* __restrict__ pos,        // [E]
    float* __restrict__ slots)          // [(A*CAP+1) * 1152]
{
    const int wid  = threadIdx.x >> 6;
    const int lane = threadIdx.x & 63;
    const int e = blockIdx.x * 4 + wid;
    if (e >= E) return;                 // wave-uniform exit; no barriers

    __shared__ __align__(16) float Msh[4][MSZ];   // wave-private sections
    __shared__ float Ysh[4][S9];

    // zero this wave's M section (27 float4)
    if (lane < 27) ((float4*)&Msh[wid][0])[lane] = make_float4(0.f, 0.f, 0.f, 0.f);

    // spherical harmonics (lane 0 -> LDS; same-wave DS is in-order)
    float dx = dir[3 * e], dy = dir[3 * e + 1], dz = dir[3 * e + 2];
    const float inv = rsqrtf(dx * dx + dy * dy + dz * dz);
    dx *= inv; dy *= inv; dz *= inv;
    if (lane == 0) {
        const float s3c  = 1.7320508075688772f;
        const float s5c  = 2.2360679774997896f;
        const float s15c = 3.8729833462074170f;
        Ysh[wid][0] = 1.0f;
        Ysh[wid][1] = s3c * dy;
        Ysh[wid][2] = s3c * dz;
        Ysh[wid][3] = s3c * dx;
        Ysh[wid][4] = s15c * dx * dy;
        Ysh[wid][5] = s15c * dy * dz;
        Ysh[wid][6] = 0.5f * s5c * (3.0f * dz * dz - 1.0f);
        Ysh[wid][7] = s15c * dx * dz;
        Ysh[wid][8] = 0.5f * s15c * (dx * dx - dy * dy);
    }

    // sparse-CG M build: ~3 LDS atomics/lane into the wave's section
    for (int k = lane; k < ncg; k += 64) {
        atomicAdd(&Msh[wid][cg_i3[k] * MROW + cg_i1[k]],
                  cg_vals[k] * Ysh[wid][cg_i2[k]]);
    }

    // radial filter: float2 per lane, one pass over Wf
    float rad[NRAD];
    #pragma unroll
    for (int r = 0; r < NRAD; ++r) rad[r] = radial[(size_t)e * NRAD + r];
    const float cut = cutoff[e];

    float2 w0 = ((const float2*)(bf + 0 * NF))[lane];
    float2 w1 = ((const float2*)(bf + 1 * NF))[lane];
    float2 w2 = ((const float2*)(bf + 2 * NF))[lane];
    #pragma unroll 4
    for (int r = 0; r < NRAD; ++r) {
        const float2* wrow = (const float2*)(Wf + r * (3 * NF));
        w0 = f2fma(rad[r], wrow[lane],       w0);
        w1 = f2fma(rad[r], wrow[lane + 64],  w1);
        w2 = f2fma(rad[r], wrow[lane + 128], w2);
    }
    w0.x *= cut; w0.y *= cut;
    w1.x *= cut; w1.y *= cut;
    w2.x *= cut; w2.y *= cut;

    // gather x[j] (j wave-uniform)
    const int j = __builtin_amdgcn_readfirstlane(idx_j[e]);
    const float2* xp = (const float2*)(x + (size_t)j * ROWF) + lane;
    float2 xj[S9];
    #pragma unroll
    for (int s = 0; s < S9; ++s) xj[s] = xp[s * 64];

    // contract + PLAIN coalesced stores into this edge's slot row
    const int row = __builtin_amdgcn_readfirstlane(pos[e]);
    float2* sp = (float2*)(slots) + (size_t)row * (ROWF / 2) + lane;

    #pragma unroll
    for (int s3 = 0; s3 < S9; ++s3) {
        const float4* mr = (const float4*)&Msh[wid][s3 * MROW];
        const float4 m0 = mr[0];
        const float4 m1 = mr[1];
        const float  m8 = Msh[wid][s3 * MROW + 8];
        float2 tsum = make_float2(0.f, 0.f);
        tsum = f2fma(m0.x, xj[0], tsum);
        tsum = f2fma(m0.y, xj[1], tsum);
        tsum = f2fma(m0.z, xj[2], tsum);
        tsum = f2fma(m0.w, xj[3], tsum);
        tsum = f2fma(m1.x, xj[4], tsum);
        tsum = f2fma(m1.y, xj[5], tsum);
        tsum = f2fma(m1.z, xj[6], tsum);
        tsum = f2fma(m1.w, xj[7], tsum);
        tsum = f2fma(m8,   xj[8], tsum);
        const float2 wl = (s3 == 0) ? w0 : ((s3 < 4) ? w1 : w2);
        sp[s3 * 64] = make_float2(wl.x * tsum.x, wl.y * tsum.y);
    }
}

// ---------- K3: 2 waves per atom (s-dim split), contiguous slot sum ----------
__global__ __launch_bounds__(256) void reduce_kernel(
    const float* __restrict__ slots, const int* __restrict__ cnt, int A,
    float* __restrict__ out)            // [A, 9, 128]
{
    const int wid  = threadIdx.x >> 6;
    const int lane = threadIdx.x & 63;
    const int a  = blockIdx.x * 2 + (wid >> 1);
    const int sh = wid & 1;              // 0: s=0..4, 1: s=5..8
    if (a >= A) return;
    const int deg = min(cnt[a], CAP);
    const int s0 = sh ? 5 : 0;
    const int ns = sh ? 4 : 5;

    float2 acc[5];
    #pragma unroll
    for (int s = 0; s < 5; ++s) acc[s] = make_float2(0.f, 0.f);

    const float2* base = (const float2*)(slots) + (size_t)a * CAP * (ROWF / 2) + lane;
    for (int p = 0; p < deg; ++p) {
        const float2* rp = base + (size_t)p * (ROWF / 2) + s0 * 64;
        #pragma unroll
        for (int s = 0; s < 5; ++s) {
            if (s < ns) {
                float2 v = rp[s * 64];
                acc[s].x += v.x; acc[s].y += v.y;
            }
        }
    }
    float2* op = (float2*)(out + (size_t)a * ROWF) + s0 * 64 + lane;
    #pragma unroll
    for (int s = 0; s < 5; ++s)
        if (s < ns) op[s * 64] = acc[s];
}

// ---------- fallback: R8 fused edge kernel with global atomics ----------
__global__ __launch_bounds__(256) void so3_edge_fused(
    const float* __restrict__ x, const float* __restrict__ radial,
    const float* __restrict__ dir, const float* __restrict__ cutoff,
    const float* __restrict__ Wf, const float* __restrict__ bf,
    const float* __restrict__ cg_vals,
    const int* __restrict__ idx_i, const int* __restrict__ idx_j,
    const int* __restrict__ cg_i1, const int* __restrict__ cg_i2,
    const int* __restrict__ cg_i3, int ncg, int E,
    float* __restrict__ out)
{
    const int wid  = threadIdx.x >> 6;
    const int lane = threadIdx.x & 63;
    const int e = blockIdx.x * 4 + wid;
    if (e >= E) return;

    __shared__ __align__(16) float Msh[4][MSZ];
    __shared__ float Ysh[4][S9];

    if (lane < 27) ((float4*)&Msh[wid][0])[lane] = make_float4(0.f, 0.f, 0.f, 0.f);

    float dx = dir[3 * e], dy = dir[3 * e + 1], dz = dir[3 * e + 2];
    const float inv = rsqrtf(dx * dx + dy * dy + dz * dz);
    dx *= inv; dy *= inv; dz *= inv;
    if (lane == 0) {
        const float s3c = 1.7320508075688772f, s5c = 2.2360679774997896f,
                    s15c = 3.8729833462074170f;
        Ysh[wid][0] = 1.0f;
        Ysh[wid][1] = s3c * dy; Ysh[wid][2] = s3c * dz; Ysh[wid][3] = s3c * dx;
        Ysh[wid][4] = s15c * dx * dy; Ysh[wid][5] = s15c * dy * dz;
        Ysh[wid][6] = 0.5f * s5c * (3.0f * dz * dz - 1.0f);
        Ysh[wid][7] = s15c * dx * dz;
        Ysh[wid][8] = 0.5f * s15c * (dx * dx - dy * dy);
    }
    for (int k = lane; k < ncg; k += 64)
        atomicAdd(&Msh[wid][cg_i3[k] * MROW + cg_i1[k]], cg_vals[k] * Ysh[wid][cg_i2[k]]);

    float rad[NRAD];
    #pragma unroll
    for (int r = 0; r < NRAD; ++r) rad[r] = radial[(size_t)e * NRAD + r];
    const float cut = cutoff[e];

    float2 w0 = ((const float2*)(bf + 0 * NF))[lane];
    float2 w1 = ((const float2*)(bf + 1 * NF))[lane];
    float2 w2 = ((const float2*)(bf + 2 * NF))[lane];
    #pragma unroll 4
    for (int r = 0; r < NRAD; ++r) {
        const float2* wrow = (const float2*)(Wf + r * (3 * NF));
        w0 = f2fma(rad[r], wrow[lane], w0);
        w1 = f2fma(rad[r], wrow[lane + 64], w1);
        w2 = f2fma(rad[r], wrow[lane + 128], w2);
    }
    w0.x *= cut; w0.y *= cut; w1.x *= cut; w1.y *= cut; w2.x *= cut; w2.y *= cut;

    const int j = __builtin_amdgcn_readfirstlane(idx_j[e]);
    const float2* xp = (const float2*)(x + (size_t)j * ROWF) + lane;
    float2 xj[S9];
    #pragma unroll
    for (int s = 0; s < S9; ++s) xj[s] = xp[s * 64];

    const int a = __builtin_amdgcn_readfirstlane(idx_i[e]);
    float* op = out + (size_t)a * ROWF + 2 * lane;
    #pragma unroll
    for (int s3 = 0; s3 < S9; ++s3) {
        const float4* mr = (const float4*)&Msh[wid][s3 * MROW];
        const float4 m0 = mr[0];
        const float4 m1 = mr[1];
        const float  m8 = Msh[wid][s3 * MROW + 8];
        float2 tsum = make_float2(0.f, 0.f);
        tsum = f2fma(m0.x, xj[0], tsum);
        tsum = f2fma(m0.y, xj[1], tsum);
        tsum = f2fma(m0.z, xj[2], tsum);
        tsum = f2fma(m0.w, xj[3], tsum);
        tsum = f2fma(m1.x, xj[4], tsum);
        tsum = f2fma(m1.y, xj[5], tsum);
        tsum = f2fma(m1.z, xj[6], tsum);
        tsum = f2fma(m1.w, xj[7], tsum);
        tsum = f2fma(m8,   xj[8], tsum);
        const float2 wl = (s3 == 0) ? w0 : ((s3 < 4) ? w1 : w2);
        atomicAdd(&op[s3 * NF],     wl.x * tsum.x);
        atomicAdd(&op[s3 * NF + 1], wl.y * tsum.y);
    }
}

extern "C" void kernel_launch(void* const* d_in, const int* in_sizes, int n_in,
                              void* d_out, int out_size, void* d_ws, size_t ws_size,
                              hipStream_t stream) {
    const float* x       = (const float*)d_in[0];
    const float* radial  = (const float*)d_in[1];
    const float* dir     = (const float*)d_in[2];
    const float* cutoff  = (const float*)d_in[3];
    const float* Wf      = (const float*)d_in[4];
    const float* bf      = (const float*)d_in[5];
    const float* cg_vals = (const float*)d_in[6];
    const int*   idx_i   = (const int*)d_in[7];
    const int*   idx_j   = (const int*)d_in[8];
    const int*   cg_i1   = (const int*)d_in[9];
    const int*   cg_i2   = (const int*)d_in[10];
    const int*   cg_i3   = (const int*)d_in[11];
    // d_in[12] = w_idx: unused (folded into kernel)

    const int E   = in_sizes[7];
    const int ncg = in_sizes[6];
    const int A   = in_sizes[0] / ROWF;

    // ws: cnt[A] | pos[E] | (align 256) | slots[(A*CAP+1) * 1152]
    int* cnt = (int*)d_ws;
    int* pos = cnt + A;
    size_t ib   = (size_t)(A + E) * sizeof(int);
    size_t soff = (ib + 255) & ~(size_t)255;
    float* slots = (float*)((char*)d_ws + soff);
    size_t need = soff + ((size_t)A * CAP + 1) * ROWF * sizeof(float);

    if (ws_size >= need) {
        hipMemsetAsync(cnt, 0, (size_t)A * sizeof(int), stream);

        prep_kernel<<<(E + 255) / 256, 256, 0, stream>>>(idx_i, E, A, cnt, pos);

        so3_edge_slots<<<(E + 3) / 4, 256, 0, stream>>>(
            x, radial, dir, cutoff, Wf, bf, cg_vals, idx_j,
            cg_i1, cg_i2, cg_i3, ncg, E, pos, slots);

        reduce_kernel<<<(A + 1) / 2, 256, 0, stream>>>(slots, cnt, A, (float*)d_out);
    } else {
        hipMemsetAsync(d_out, 0, (size_t)out_size * sizeof(float), stream);
        so3_edge_fused<<<(E + 3) / 4, 256, 0, stream>>>(
            x, radial, dir, cutoff, Wf, bf, cg_vals, idx_i, idx_j,
            cg_i1, cg_i2, cg_i3, ncg, E, (float*)d_out);
    }
}

// Round 15
// 128.708 us; speedup vs baseline: 1.0294x; 1.0294x over previous
//
#include <hip/hip_runtime.h>
#include <math.h>

// SO3 convolution lmax=2 — 3 dispatches: memset(cnt) + edge-parallel compute
// with inline slot assignment + block-per-atom reduce.
//   K1) so3_edge_slots: ONE wave per edge, 8 waves per 512-thr block.
//       Lane 0 claims a dense per-atom slot (atomicAdd on cnt[a], ~12k tiny
//       atomics total) and broadcasts the row via shfl — prep kernel folded
//       away. Then (R8/R14's proven body): Y -> wave-private LDS, M via LDS
//       atomics, radial filter Wf pass, x[idx_j] gather, 9x9 contract,
//       9 PLAIN coalesced float2 stores to slots[row]. No barriers.
//   K2) reduce_kernel: block per atom, 4 waves; wave w sums slot rows
//       p = w, w+4, ... (reads fully parallel), one LDS cross-wave combine,
//       wave 0 stores the atom's out row (deg-0 -> zeros).
//   No global float atomics. Fallback (ws too small): R8 fused-atomic kernel.

#define S9     9
#define MROW   12
#define MSZ    (S9 * MROW)      // 108
#define NF     128
#define NRAD   20
#define CAP    32               // slots per atom (P(deg>32) ~ 0, Poisson(10))
#define ROWF   (S9 * NF)        // 1152 floats per slot row
#define EPB    8                // edges (waves) per block in K1

__device__ inline float2 f2fma(float a, float2 b, float2 c) {
    return make_float2(fmaf(a, b.x, c.x), fmaf(a, b.y, c.y));
}

// ---------- K1: one wave per edge, inline slot claim, plain stores ----------
__global__ __launch_bounds__(512) void so3_edge_slots(
    const float* __restrict__ x,        // [A, 9, 128]
    const float* __restrict__ radial,   // [E, 20]
    const float* __restrict__ dir,      // [E, 3]
    const float* __restrict__ cutoff,   // [E]
    const float* __restrict__ Wf,       // [20, 384]
    const float* __restrict__ bf,       // [384]
    const float* __restrict__ cg_vals,
    const int* __restrict__ idx_i,
    const int* __restrict__ idx_j,
    const int* __restrict__ cg_i1,
    const int* __restrict__ cg_i2,
    const int* __restrict__ cg_i3,
    int ncg, int E, int A,
    int* __restrict__ cnt,              // [A], pre-zeroed
    float* __restrict__ slots)          // [(A*CAP+1) * 1152]
{
    const int wid  = threadIdx.x >> 6;
    const int lane = threadIdx.x & 63;
    const int e = blockIdx.x * EPB + wid;
    if (e >= E) return;                 // wave-uniform exit; no barriers

    __shared__ __align__(16) float Msh[EPB][MSZ];   // wave-private sections
    __shared__ float Ysh[EPB][S9];

    // claim slot row early (store-path only; overlaps all compute)
    int row = 0;
    if (lane == 0) {
        const int a = idx_i[e];
        const int p = atomicAdd(&cnt[a], 1);
        row = (p < CAP) ? (a * CAP + p) : (A * CAP);
    }
    row = __shfl(row, 0);

    // zero this wave's M section (27 float4)
    if (lane < 27) ((float4*)&Msh[wid][0])[lane] = make_float4(0.f, 0.f, 0.f, 0.f);

    // spherical harmonics (lane 0 -> LDS; same-wave DS is in-order)
    float dx = dir[3 * e], dy = dir[3 * e + 1], dz = dir[3 * e + 2];
    const float inv = rsqrtf(dx * dx + dy * dy + dz * dz);
    dx *= inv; dy *= inv; dz *= inv;
    if (lane == 0) {
        const float s3c  = 1.7320508075688772f;
        const float s5c  = 2.2360679774997896f;
        const float s15c = 3.8729833462074170f;
        Ysh[wid][0] = 1.0f;
        Ysh[wid][1] = s3c * dy;
        Ysh[wid][2] = s3c * dz;
        Ysh[wid][3] = s3c * dx;
        Ysh[wid][4] = s15c * dx * dy;
        Ysh[wid][5] = s15c * dy * dz;
        Ysh[wid][6] = 0.5f * s5c * (3.0f * dz * dz - 1.0f);
        Ysh[wid][7] = s15c * dx * dz;
        Ysh[wid][8] = 0.5f * s15c * (dx * dx - dy * dy);
    }

    // sparse-CG M build: ~3 LDS atomics/lane into the wave's section
    for (int k = lane; k < ncg; k += 64) {
        atomicAdd(&Msh[wid][cg_i3[k] * MROW + cg_i1[k]],
                  cg_vals[k] * Ysh[wid][cg_i2[k]]);
    }

    // radial filter: float2 per lane, one pass over Wf
    float rad[NRAD];
    #pragma unroll
    for (int r = 0; r < NRAD; ++r) rad[r] = radial[(size_t)e * NRAD + r];
    const float cut = cutoff[e];

    float2 w0 = ((const float2*)(bf + 0 * NF))[lane];
    float2 w1 = ((const float2*)(bf + 1 * NF))[lane];
    float2 w2 = ((const float2*)(bf + 2 * NF))[lane];
    #pragma unroll 4
    for (int r = 0; r < NRAD; ++r) {
        const float2* wrow = (const float2*)(Wf + r * (3 * NF));
        w0 = f2fma(rad[r], wrow[lane],       w0);
        w1 = f2fma(rad[r], wrow[lane + 64],  w1);
        w2 = f2fma(rad[r], wrow[lane + 128], w2);
    }
    w0.x *= cut; w0.y *= cut;
    w1.x *= cut; w1.y *= cut;
    w2.x *= cut; w2.y *= cut;

    // gather x[j] (j wave-uniform)
    const int j = __builtin_amdgcn_readfirstlane(idx_j[e]);
    const float2* xp = (const float2*)(x + (size_t)j * ROWF) + lane;
    float2 xj[S9];
    #pragma unroll
    for (int s = 0; s < S9; ++s) xj[s] = xp[s * 64];

    // contract + PLAIN coalesced stores into this edge's slot row
    float2* sp = (float2*)(slots) + (size_t)row * (ROWF / 2) + lane;

    #pragma unroll
    for (int s3 = 0; s3 < S9; ++s3) {
        const float4* mr = (const float4*)&Msh[wid][s3 * MROW];
        const float4 m0 = mr[0];
        const float4 m1 = mr[1];
        const float  m8 = Msh[wid][s3 * MROW + 8];
        float2 tsum = make_float2(0.f, 0.f);
        tsum = f2fma(m0.x, xj[0], tsum);
        tsum = f2fma(m0.y, xj[1], tsum);
        tsum = f2fma(m0.z, xj[2], tsum);
        tsum = f2fma(m0.w, xj[3], tsum);
        tsum = f2fma(m1.x, xj[4], tsum);
        tsum = f2fma(m1.y, xj[5], tsum);
        tsum = f2fma(m1.z, xj[6], tsum);
        tsum = f2fma(m1.w, xj[7], tsum);
        tsum = f2fma(m8,   xj[8], tsum);
        const float2 wl = (s3 == 0) ? w0 : ((s3 < 4) ? w1 : w2);
        sp[s3 * 64] = make_float2(wl.x * tsum.x, wl.y * tsum.y);
    }
}

// ---------- K2: block per atom, 4 waves over slots, LDS combine ----------
__global__ __launch_bounds__(256) void reduce_kernel(
    const float* __restrict__ slots, const int* __restrict__ cnt,
    float* __restrict__ out)            // [A, 9, 128]
{
    const int a    = blockIdx.x;
    const int wid  = threadIdx.x >> 6;
    const int lane = threadIdx.x & 63;
    const int deg = min(cnt[a], CAP);

    __shared__ float red[3][ROWF];      // 13824 B

    float2 acc[S9];
    #pragma unroll
    for (int s = 0; s < S9; ++s) acc[s] = make_float2(0.f, 0.f);

    const float2* base = (const float2*)(slots) + (size_t)a * CAP * (ROWF / 2) + lane;
    for (int p = wid; p < deg; p += 4) {
        const float2* rp = base + (size_t)p * (ROWF / 2);
        #pragma unroll
        for (int s = 0; s < S9; ++s) {
            float2 v = rp[s * 64];
            acc[s].x += v.x; acc[s].y += v.y;
        }
    }

    if (wid > 0) {
        float2* rp = (float2*)&red[wid - 1][0];
        #pragma unroll
        for (int s = 0; s < S9; ++s) rp[s * 64 + lane] = acc[s];
    }
    __syncthreads();
    if (wid == 0) {
        #pragma unroll
        for (int r2 = 0; r2 < 3; ++r2) {
            const float2* rp = (const float2*)&red[r2][0];
            #pragma unroll
            for (int s = 0; s < S9; ++s) {
                float2 v = rp[s * 64 + lane];
                acc[s].x += v.x; acc[s].y += v.y;
            }
        }
        float2* op = (float2*)(out + (size_t)a * ROWF) + lane;
        #pragma unroll
        for (int s = 0; s < S9; ++s) op[s * 64] = acc[s];
    }
}

// ---------- fallback: R8 fused edge kernel with global atomics ----------
__global__ __launch_bounds__(256) void so3_edge_fused(
    const float* __restrict__ x, const float* __restrict__ radial,
    const float* __restrict__ dir, const float* __restrict__ cutoff,
    const float* __restrict__ Wf, const float* __restrict__ bf,
    const float* __restrict__ cg_vals,
    const int* __restrict__ idx_i, const int* __restrict__ idx_j,
    const int* __restrict__ cg_i1, const int* __restrict__ cg_i2,
    const int* __restrict__ cg_i3, int ncg, int E,
    float* __restrict__ out)
{
    const int wid  = threadIdx.x >> 6;
    const int lane = threadIdx.x & 63;
    const int e = blockIdx.x * 4 + wid;
    if (e >= E) return;

    __shared__ __align__(16) float Msh[4][MSZ];
    __shared__ float Ysh[4][S9];

    if (lane < 27) ((float4*)&Msh[wid][0])[lane] = make_float4(0.f, 0.f, 0.f, 0.f);

    float dx = dir[3 * e], dy = dir[3 * e + 1], dz = dir[3 * e + 2];
    const float inv = rsqrtf(dx * dx + dy * dy + dz * dz);
    dx *= inv; dy *= inv; dz *= inv;
    if (lane == 0) {
        const float s3c = 1.7320508075688772f, s5c = 2.2360679774997896f,
                    s15c = 3.8729833462074170f;
        Ysh[wid][0] = 1.0f;
        Ysh[wid][1] = s3c * dy; Ysh[wid][2] = s3c * dz; Ysh[wid][3] = s3c * dx;
        Ysh[wid][4] = s15c * dx * dy; Ysh[wid][5] = s15c * dy * dz;
        Ysh[wid][6] = 0.5f * s5c * (3.0f * dz * dz - 1.0f);
        Ysh[wid][7] = s15c * dx * dz;
        Ysh[wid][8] = 0.5f * s15c * (dx * dx - dy * dy);
    }
    for (int k = lane; k < ncg; k += 64)
        atomicAdd(&Msh[wid][cg_i3[k] * MROW + cg_i1[k]], cg_vals[k] * Ysh[wid][cg_i2[k]]);

    float rad[NRAD];
    #pragma unroll
    for (int r = 0; r < NRAD; ++r) rad[r] = radial[(size_t)e * NRAD + r];
    const float cut = cutoff[e];

    float2 w0 = ((const float2*)(bf + 0 * NF))[lane];
    float2 w1 = ((const float2*)(bf + 1 * NF))[lane];
    float2 w2 = ((const float2*)(bf + 2 * NF))[lane];
    #pragma unroll 4
    for (int r = 0; r < NRAD; ++r) {
        const float2* wrow = (const float2*)(Wf + r * (3 * NF));
        w0 = f2fma(rad[r], wrow[lane], w0);
        w1 = f2fma(rad[r], wrow[lane + 64], w1);
        w2 = f2fma(rad[r], wrow[lane + 128], w2);
    }
    w0.x *= cut; w0.y *= cut; w1.x *= cut; w1.y *= cut; w2.x *= cut; w2.y *= cut;

    const int j = __builtin_amdgcn_readfirstlane(idx_j[e]);
    const float2* xp = (const float2*)(x + (size_t)j * ROWF) + lane;
    float2 xj[S9];
    #pragma unroll
    for (int s = 0; s < S9; ++s) xj[s] = xp[s * 64];

    const int a = __builtin_amdgcn_readfirstlane(idx_i[e]);
    float* op = out + (size_t)a * ROWF + 2 * lane;
    #pragma unroll
    for (int s3 = 0; s3 < S9; ++s3) {
        const float4* mr = (const float4*)&Msh[wid][s3 * MROW];
        const float4 m0 = mr[0];
        const float4 m1 = mr[1];
        const float  m8 = Msh[wid][s3 * MROW + 8];
        float2 tsum = make_float2(0.f, 0.f);
        tsum = f2fma(m0.x, xj[0], tsum);
        tsum = f2fma(m0.y, xj[1], tsum);
        tsum = f2fma(m0.z, xj[2], tsum);
        tsum = f2fma(m0.w, xj[3], tsum);
        tsum = f2fma(m1.x, xj[4], tsum);
        tsum = f2fma(m1.y, xj[5], tsum);
        tsum = f2fma(m1.z, xj[6], tsum);
        tsum = f2fma(m1.w, xj[7], tsum);
        tsum = f2fma(m8,   xj[8], tsum);
        const float2 wl = (s3 == 0) ? w0 : ((s3 < 4) ? w1 : w2);
        atomicAdd(&op[s3 * NF],     wl.x * tsum.x);
        atomicAdd(&op[s3 * NF + 1], wl.y * tsum.y);
    }
}

extern "C" void kernel_launch(void* const* d_in, const int* in_sizes, int n_in,
                              void* d_out, int out_size, void* d_ws, size_t ws_size,
                              hipStream_t stream) {
    const float* x       = (const float*)d_in[0];
    const float* radial  = (const float*)d_in[1];
    const float* dir     = (const float*)d_in[2];
    const float* cutoff  = (const float*)d_in[3];
    const float* Wf      = (const float*)d_in[4];
    const float* bf      = (const float*)d_in[5];
    const float* cg_vals = (const float*)d_in[6];
    const int*   idx_i   = (const int*)d_in[7];
    const int*   idx_j   = (const int*)d_in[8];
    const int*   cg_i1   = (const int*)d_in[9];
    const int*   cg_i2   = (const int*)d_in[10];
    const int*   cg_i3   = (const int*)d_in[11];
    // d_in[12] = w_idx: unused (folded into kernel)

    const int E   = in_sizes[7];
    const int ncg = in_sizes[6];
    const int A   = in_sizes[0] / ROWF;

    // ws: cnt[A] | (align 256) | slots[(A*CAP+1) * 1152]
    int* cnt = (int*)d_ws;
    size_t soff = (((size_t)A * sizeof(int)) + 255) & ~(size_t)255;
    float* slots = (float*)((char*)d_ws + soff);
    size_t need = soff + ((size_t)A * CAP + 1) * ROWF * sizeof(float);

    if (ws_size >= need) {
        hipMemsetAsync(cnt, 0, (size_t)A * sizeof(int), stream);

        so3_edge_slots<<<(E + EPB - 1) / EPB, 64 * EPB, 0, stream>>>(
            x, radial, dir, cutoff, Wf, bf, cg_vals, idx_i, idx_j,
            cg_i1, cg_i2, cg_i3, ncg, E, A, cnt, slots);

        reduce_kernel<<<A, 256, 0, stream>>>(slots, cnt, (float*)d_out);
    } else {
        hipMemsetAsync(d_out, 0, (size_t)out_size * sizeof(float), stream);
        so3_edge_fused<<<(E + 3) / 4, 256, 0, stream>>>(
            x, radial, dir, cutoff, Wf, bf, cg_vals, idx_i, idx_j,
            cg_i1, cg_i2, cg_i3, ncg, E, (float*)d_out);
    }
}